// Round 9
// baseline (328.196 us; speedup 1.0000x reference)
//
#include <hip/hip_runtime.h>
#include <hip/hip_bf16.h>

// Fused causal MHA: qkv proj -> flash attention (kv-split + 3-stage pipeline) ->
// out proj. B=2 T=2048 D=1024 H=16 hd=64; softmax in log2 domain.

typedef __bf16 bf16;
typedef float f32x4 __attribute__((ext_vector_type(4)));
typedef float f32x16 __attribute__((ext_vector_type(16)));
typedef bf16 bf16x4 __attribute__((ext_vector_type(4)));
typedef bf16 bf16x8 __attribute__((ext_vector_type(8)));

#define B_ 2
#define T_ 2048
#define D_ 1024
#define H_ 16
#define HD_ 64
#define QSPLIT 9  // qt >= QSPLIT gets 2 kv-segments

__device__ __forceinline__ f32x16 mfma32(bf16x8 a, bf16x8 b, f32x16 c) {
    return __builtin_amdgcn_mfma_f32_32x32x16_bf16(a, b, c, 0, 0, 0);
}

// async global->LDS, 16B per lane (wave-uniform LDS base + lane*16)
__device__ __forceinline__ void gload16(void* l, const void* g) {
    __builtin_amdgcn_global_load_lds(
        (const __attribute__((address_space(1))) unsigned int*)g,
        (__attribute__((address_space(3))) unsigned int*)l, 16, 0, 0);
}

__device__ __forceinline__ f32x16 z16() {
    f32x16 v;
#pragma unroll
    for (int i = 0; i < 16; ++i) v[i] = 0.f;
    return v;
}

// ---------------- cast kernels ----------------
__global__ __launch_bounds__(256) void cast_f32_bf16(const float* __restrict__ in,
                                                     bf16* __restrict__ out, int n4) {
    int i = blockIdx.x * 256 + threadIdx.x;
    if (i < n4) {
        float4 v = ((const float4*)in)[i];
        bf16x4 o = { (bf16)v.x, (bf16)v.y, (bf16)v.z, (bf16)v.w };
        ((bf16x4*)out)[i] = o;
    }
}

// in [R][C] f32 -> out [C][R] bf16
__global__ __launch_bounds__(256) void cast_transpose(const float* __restrict__ in,
                                                      bf16* __restrict__ out, int R, int C) {
    __shared__ float tile[32][33];
    int cx = blockIdx.x * 32 + threadIdx.x;
    int r0 = blockIdx.y * 32;
#pragma unroll
    for (int j = 0; j < 32; j += 8)
        tile[threadIdx.y + j][threadIdx.x] = in[(size_t)(r0 + threadIdx.y + j) * C + cx];
    __syncthreads();
    int rx = r0 + threadIdx.x;
    int c0 = blockIdx.x * 32;
#pragma unroll
    for (int j = 0; j < 32; j += 8)
        out[(size_t)(c0 + threadIdx.y + j) * R + rx] = (bf16)tile[threadIdx.x][threadIdx.y + j];
}

// V [bh][T][64] bf16 -> Vt [bh][64][T] bf16 (64x64 tiles, conflict-free LDS)
__global__ __launch_bounds__(256) void transpose_v(const bf16* __restrict__ vb,
                                                   bf16* __restrict__ vt) {
    __shared__ bf16 st[64 * 65];
    const int bh = blockIdx.y;
    const int t0 = blockIdx.x * 64;
    const int tid = threadIdx.x;
#pragma unroll
    for (int c = 0; c < 2; ++c) {
        int cid = tid + c * 256;
        int r = cid >> 3, col = (cid & 7) * 8;
        bf16x8 v = *(const bf16x8*)&vb[((size_t)bh * T_ + t0 + r) * HD_ + col];
#pragma unroll
        for (int j = 0; j < 8; ++j) st[r * 65 + col + j] = v[j];
    }
    __syncthreads();
#pragma unroll
    for (int c = 0; c < 2; ++c) {
        int cid = tid + c * 256;
        int tg = cid & 7, d = cid >> 3;
        bf16x8 o;
#pragma unroll
        for (int j = 0; j < 8; ++j) o[j] = st[(tg * 8 + j) * 65 + d];
        *(bf16x8*)&vt[((size_t)bh * HD_ + d) * T_ + t0 + tg * 8] = o;
    }
}

// ---------------- GEMM: C[M,N] = A[M,K] * Bt[N,K]^T, 32x32x16 MFMA ----------------
template <int MW, int NWN, int EPI>
__global__ __launch_bounds__(256) void gemm_k(
    const bf16* __restrict__ A, const bf16* __restrict__ Bt,
    int M, int N, int K,
    bf16* __restrict__ qb, bf16* __restrict__ kb, bf16* __restrict__ vb,
    const float* __restrict__ bias, float* __restrict__ outf) {
    constexpr int BM = 64 * MW;
    constexpr int BN = 64 * NWN;
    __shared__ bf16 sA[BM * 64];
    __shared__ bf16 sB[BN * 64];
    const int tid = threadIdx.x;
    const int wave = tid >> 6, lane = tid & 63;
    const int ln = lane & 31, hi = lane >> 5;
    const int wr = (wave >> 1) * (32 * MW);
    const int wc = (wave & 1) * (32 * NWN);
    const int m0 = blockIdx.x * BM, n0 = blockIdx.y * BN;

    f32x16 acc[MW][NWN];
#pragma unroll
    for (int mi = 0; mi < MW; ++mi)
#pragma unroll
        for (int ni = 0; ni < NWN; ++ni) acc[mi][ni] = z16();

    for (int k0 = 0; k0 < K; k0 += 64) {
        __syncthreads();
#pragma unroll
        for (int j = 0; j < 2 * MW; ++j) {
            int c = tid + 256 * j;
            int r = c >> 3, g = (c & 7) ^ (r & 7);
            gload16(&sA[c * 8], A + (size_t)(m0 + r) * K + k0 + 8 * g);
        }
#pragma unroll
        for (int j = 0; j < 2 * NWN; ++j) {
            int c = tid + 256 * j;
            int r = c >> 3, g = (c & 7) ^ (r & 7);
            gload16(&sB[c * 8], Bt + (size_t)(n0 + r) * K + k0 + 8 * g);
        }
        __syncthreads();
#pragma unroll
        for (int s = 0; s < 4; ++s) {
            bf16x8 av[MW], bv[NWN];
#pragma unroll
            for (int mi = 0; mi < MW; ++mi) {
                int r = wr + mi * 32 + ln;
                av[mi] = *(const bf16x8*)((const char*)sA + r * 128 +
                                          ((((s << 1) | hi) ^ (r & 7)) << 4));
            }
#pragma unroll
            for (int ni = 0; ni < NWN; ++ni) {
                int r = wc + ni * 32 + ln;
                bv[ni] = *(const bf16x8*)((const char*)sB + r * 128 +
                                          ((((s << 1) | hi) ^ (r & 7)) << 4));
            }
#pragma unroll
            for (int mi = 0; mi < MW; ++mi)
#pragma unroll
                for (int ni = 0; ni < NWN; ++ni)
                    acc[mi][ni] = mfma32(av[mi], bv[ni], acc[mi][ni]);
        }
    }

    // epilogue: C/D layout col=lane&31, row=(r&3)+8*(r>>2)+4*hi
#pragma unroll
    for (int mi = 0; mi < MW; ++mi)
#pragma unroll
        for (int ni = 0; ni < NWN; ++ni)
#pragma unroll
            for (int r = 0; r < 16; ++r) {
                int row = m0 + wr + mi * 32 + (r & 3) + 8 * (r >> 2) + 4 * hi;
                int col = n0 + wc + ni * 32 + ln;
                float v = acc[mi][ni][r];
                if (EPI == 0) {
                    int part = col >> 10, h = (col >> 6) & 15, d = col & 63;
                    int b = row >> 11, t = row & (T_ - 1);
                    size_t idx = ((size_t)(b * H_ + h) * T_ + t) * HD_ + d;
                    bf16* dst = (part == 0) ? qb : (part == 1) ? kb : vb;
                    dst[idx] = (bf16)v;
                } else {
                    outf[(size_t)row * N + col] = v + bias[col];
                }
            }
}

// ---------------- flash attention: swapped 32x32 MFMA, 3-stage pipeline ------
// Per tile t: DMA(t+2)->b2 | QK(t+1)<-b1 (MFMA) overlapping softmax(t) (VALU)
// | PV(t)<-b0 (MFMA) | barrier. Buffers rotate mod 3; 1 barrier per tile.
__device__ __forceinline__ bf16x8 kread(const char* base, int row, int s, int hi) {
    int b = (row * 128 + s * 32 + hi * 16) ^ ((row & 7) << 4);
    return *(const bf16x8*)(base + b);
}
__device__ __forceinline__ bf16x8 vread(const char* base, int row, int s, int hi) {
    int sw = (row & 7) << 4;
    int b0 = (row * 128 + s * 32 + hi * 8) ^ sw;
    int b1 = (row * 128 + s * 32 + hi * 8 + 16) ^ sw;
    bf16x4 lo = *(const bf16x4*)(base + b0);
    bf16x4 hi4 = *(const bf16x4*)(base + b1);
    return __builtin_shufflevector(lo, hi4, 0, 1, 2, 3, 4, 5, 6, 7);
}

__global__ __launch_bounds__(256, 3) void attn_kernel(
    const bf16* __restrict__ qb, const bf16* __restrict__ kb,
    const bf16* __restrict__ vtb, bf16* __restrict__ ob,
    bf16* __restrict__ oP, float2* __restrict__ mlP) {
    __shared__ bf16 sK3[3][4096];  // [64 kv][64 hd], 128B rows, chunk-swizzled
    __shared__ bf16 sV3[3][4096];  // [64 d][64 kv], 128B rows, chunk-swizzled

    const int bid = blockIdx.x;
    const int bh = bid & 31;
    const int sid = bid >> 5;  // 0..22
    int qt, seg, t0, t1;
    if (sid < QSPLIT) {
        qt = sid; seg = -1; t0 = 0; t1 = 2 * qt + 2;
    } else {
        int idx = sid - QSPLIT;
        qt = QSPLIT + (idx >> 1);
        seg = idx & 1;
        if (seg == 0) { t0 = 0; t1 = qt + 1; }
        else          { t0 = qt + 1; t1 = 2 * qt + 2; }
    }
    const int b = bh >> 4, h = bh & 15;
    const int tid = threadIdx.x, wave = tid >> 6, lane = tid & 63;
    const int ln = lane & 31, hi = lane >> 5;
    const int qs = qt * 128 + wave * 32;
    const int qrow = qs + ln;

    const bf16* Qg = qb + (size_t)bh * (T_ * HD_);
    const bf16* Kg = kb + (size_t)bh * (T_ * HD_);
    const bf16* Vtg = vtb + (size_t)bh * (HD_ * T_);

    // Q fragments, scale 0.125*log2(e) folded in (softmax in log2 domain)
    bf16x8 qf[4];
#pragma unroll
    for (int s = 0; s < 4; ++s) {
        bf16x8 v = *(const bf16x8*)&Qg[(size_t)qrow * HD_ + s * 16 + hi * 8];
#pragma unroll
        for (int e = 0; e < 8; ++e) v[e] = (bf16)((float)v[e] * 0.1803368801f);
        qf[s] = v;
    }
    bf16x8 ones;
#pragma unroll
    for (int e = 0; e < 8; ++e) ones[e] = (bf16)1.0f;

    // staging geometry: linear chunk c -> row r=c>>3, source chunk g=(c&7)^(r&7)
    const int rr0 = tid >> 3;
    const int gg = ((tid & 7) ^ (rr0 & 7)) * 8;

    auto stage = [&](int t, int buf) {
        int kv0 = t * 64;
        gload16(&sK3[buf][tid * 8], Kg + (size_t)(kv0 + rr0) * HD_ + gg);
        gload16(&sK3[buf][(tid + 256) * 8], Kg + (size_t)(kv0 + rr0 + 32) * HD_ + gg);
        gload16(&sV3[buf][tid * 8], Vtg + (size_t)rr0 * T_ + kv0 + gg);
        gload16(&sV3[buf][(tid + 256) * 8], Vtg + (size_t)(rr0 + 32) * T_ + kv0 + gg);
    };
    auto qk = [&](int buf, f32x16& q0, f32x16& q1) {
        const char* kbase = (const char*)sK3[buf];
        q0 = z16(); q1 = z16();
        __builtin_amdgcn_s_setprio(1);
#pragma unroll
        for (int s = 0; s < 4; ++s) {
            q0 = mfma32(kread(kbase, ln, s, hi), qf[s], q0);
            q1 = mfma32(kread(kbase, ln + 32, s, hi), qf[s], q1);
        }
        __builtin_amdgcn_s_setprio(0);
    };

    // prologue: fill pipeline
    stage(t0, 0);
    __syncthreads();  // drain b0
    if (t0 + 1 < t1) stage(t0 + 1, 1);
    f32x16 pA0, pA1, pB0, pB1;
    qk(0, pA0, pA1);
    __syncthreads();  // drain b1

    const float NINF = -__builtin_inff();
    f32x16 oA = z16(), oB = z16();
    float mR = NINF, lR = 0.f;
    int c = 0;

    auto step = [&](int t, f32x16& pc0, f32x16& pc1, f32x16& pn0, f32x16& pn1) {
        const int bn = (c + 1 == 3) ? 0 : c + 1;
        const int b2 = (bn + 1 == 3) ? 0 : bn + 1;
        if (t + 2 < t1) stage(t + 2, b2);  // async DMA (drained by this step's barrier)
        if (t + 1 < t1 && 64 * (t + 1) <= qs + 31) qk(bn, pn0, pn1);  // overlaps VALU below

        if (64 * t <= qs + 31) {  // wave active for this tile
            if (64 * t + 63 > qs) {  // diagonal tile: causal mask
                int kvb = 64 * t + 4 * hi;
#pragma unroll
                for (int r = 0; r < 16; ++r) {
                    int kvr = kvb + (r & 3) + 8 * (r >> 2);
                    if (kvr > qrow) pc0[r] = NINF;
                    if (kvr + 32 > qrow) pc1[r] = NINF;
                }
            }
            // max reduce (max3-shaped)
            float mx0 = NINF, mx1 = NINF, mx2 = NINF, mx3 = NINF;
#pragma unroll
            for (int r = 0; r < 16; r += 4) {
                mx0 = fmaxf(fmaxf(pc0[r], pc1[r]), mx0);
                mx1 = fmaxf(fmaxf(pc0[r + 1], pc1[r + 1]), mx1);
                mx2 = fmaxf(fmaxf(pc0[r + 2], pc1[r + 2]), mx2);
                mx3 = fmaxf(fmaxf(pc0[r + 3], pc1[r + 3]), mx3);
            }
            float pm = fmaxf(fmaxf(mx0, mx1), fmaxf(mx2, mx3));
            pm = fmaxf(pm, __shfl_xor(pm, 32));

            // T13 defer-max
            if (__any(pm > mR + 8.f)) {
                float mnew = fmaxf(mR, pm);
                float fac = exp2f(mR - mnew);
                lR *= fac;
#pragma unroll
                for (int r = 0; r < 16; ++r) { oA[r] *= fac; oB[r] *= fac; }
                mR = mnew;
            }

            // exp2 -> bf16 pack
            bf16x8 pa0, pa1, pa2, pa3;
#pragma unroll
            for (int e = 0; e < 8; ++e) {
                pa0[e] = (bf16)exp2f(pc0[e] - mR);
                pa1[e] = (bf16)exp2f(pc0[8 + e] - mR);
                pa2[e] = (bf16)exp2f(pc1[e] - mR);
                pa3[e] = (bf16)exp2f(pc1[8 + e] - mR);
            }

            const char* vbase = (const char*)sV3[c];
            __builtin_amdgcn_s_setprio(1);
            // row-sum via ones-MFMA (every D row = column sums of P)
            f32x16 sacc = mfma32(ones, pa0, z16());
            sacc = mfma32(ones, pa1, sacc);
            sacc = mfma32(ones, pa2, sacc);
            sacc = mfma32(ones, pa3, sacc);
#pragma unroll
            for (int s = 0; s < 4; ++s) {
                bf16x8 pas = (s == 0) ? pa0 : (s == 1) ? pa1 : (s == 2) ? pa2 : pa3;
                oA = mfma32(vread(vbase, ln, s, hi), pas, oA);
                oB = mfma32(vread(vbase, ln + 32, s, hi), pas, oB);
            }
            __builtin_amdgcn_s_setprio(0);
            lR += sacc[0];
        }

        __syncthreads();  // drains DMA(t+2); all reads of buf c complete
        c = bn;
    };

    for (int t = t0; t < t1; t += 2) {
        step(t, pA0, pA1, pB0, pB1);
        if (t + 1 < t1) step(t + 1, pB0, pB1, pA0, pA1);
    }

    if (seg < 0) {
        // final: normalized write to ob [B][T][H*64]
        float inv = 1.f / lR;
        bf16* orow = ob + ((size_t)(b * T_ + qrow)) * D_ + h * HD_;
#pragma unroll
        for (int g = 0; g < 4; ++g) {
            bf16x4 w, w2;
#pragma unroll
            for (int j = 0; j < 4; ++j) {
                w[j] = (bf16)(oA[4 * g + j] * inv);
                w2[j] = (bf16)(oB[4 * g + j] * inv);
            }
            *(bf16x4*)&orow[4 * hi + 8 * g] = w;
            *(bf16x4*)&orow[32 + 4 * hi + 8 * g] = w2;
        }
    } else {
        // partial: unnormalized O + (m,l)
        int row = wave * 32 + ln;
        size_t sbase = (((size_t)bh * (16 - QSPLIT) + (qt - QSPLIT)) * 2 + seg);
        bf16* prow = oP + (sbase * 128 + row) * 64;
#pragma unroll
        for (int g = 0; g < 4; ++g) {
            bf16x4 w, w2;
#pragma unroll
            for (int j = 0; j < 4; ++j) {
                w[j] = (bf16)oA[4 * g + j];
                w2[j] = (bf16)oB[4 * g + j];
            }
            *(bf16x4*)&prow[4 * hi + 8 * g] = w;
            *(bf16x4*)&prow[32 + 4 * hi + 8 * g] = w2;
        }
        if (hi == 0) mlP[sbase * 128 + row] = make_float2(mR, lR);
    }
}

// merge 2 kv-segments per split q-strip: one thread per q-row
__global__ __launch_bounds__(256) void attn_merge(
    const bf16* __restrict__ oP, const float2* __restrict__ mlP,
    bf16* __restrict__ ob) {
    constexpr int NQS = 16 - QSPLIT;  // 7
    int gid = blockIdx.x * 256 + threadIdx.x;  // 32*NQS*128 total
    int bh = gid / (NQS * 128);
    int rem = gid - bh * (NQS * 128);
    int qi = rem >> 7, row = rem & 127;
    int b = bh >> 4, h = bh & 15;
    int t = (QSPLIT + qi) * 128 + row;
    size_t sbase = ((size_t)bh * NQS + qi) * 2;
    float2 ml0 = mlP[(sbase + 0) * 128 + row];
    float2 ml1 = mlP[(sbase + 1) * 128 + row];
    float ms = fmaxf(ml0.x, ml1.x);
    float w0 = exp2f(ml0.x - ms), w1 = exp2f(ml1.x - ms);
    float inv = 1.f / (ml0.y * w0 + ml1.y * w1);
    w0 *= inv; w1 *= inv;
    const bf16* r0 = oP + ((sbase + 0) * 128 + row) * 64;
    const bf16* r1 = oP + ((sbase + 1) * 128 + row) * 64;
    bf16* dst = ob + ((size_t)(b * T_ + t)) * D_ + h * HD_;
#pragma unroll
    for (int g = 0; g < 8; ++g) {
        bf16x8 a = *(const bf16x8*)&r0[g * 8];
        bf16x8 c = *(const bf16x8*)&r1[g * 8];
        bf16x8 o;
#pragma unroll
        for (int j = 0; j < 8; ++j)
            o[j] = (bf16)((float)a[j] * w0 + (float)c[j] * w1);
        *(bf16x8*)&dst[g * 8] = o;
    }
}

// ---------------- launch ----------------
extern "C" void kernel_launch(void* const* d_in, const int* in_sizes, int n_in,
                              void* d_out, int out_size, void* d_ws, size_t ws_size,
                              hipStream_t stream) {
    const float* x = (const float*)d_in[0];
    const float* w_qkv = (const float*)d_in[1];
    const float* w_proj = (const float*)d_in[2];
    const float* b_proj = (const float*)d_in[3];
    float* out = (float*)d_out;
    char* ws = (char*)d_ws;

    // ws layout (40 MB total, aliased by liveness):
    bf16* xb = (bf16*)(ws);                 // [4096][1024]  8MB ; dead after GEMM1
    bf16* ob = (bf16*)(ws);                 // alias: attn out (written after xb dead)
    bf16* wqkvt = (bf16*)(ws + 8388608);    // [3072][1024]  6MB ; dead after GEMM1
    bf16* vtbuf = (bf16*)(ws + 8388608);    // alias: [bh][64][T] 8MB
    bf16* qbuf = (bf16*)(ws + 16777216);    // [bh][T][64]   8MB
    bf16* wprojt = (bf16*)(ws + 16777216);  // alias: [1024][1024] 2MB (after attn)
    bf16* kbuf = (bf16*)(ws + 25165824);    // [bh][T][64]   8MB
    bf16* vbuf = (bf16*)(ws + 33554432);    // [bh][T][64]   8MB ; dead after transpose_v
    bf16* oP = (bf16*)(ws + 33554432);      // alias: partial O [32][7][2][128][64] 7.34MB
    float2* mlP = (float2*)(ws + 33554432 + 7340032);  // [32][7][2][128] 448KB

    cast_f32_bf16<<<4096, 256, 0, stream>>>(x, xb, (B_ * T_ * D_) / 4);
    dim3 tb(32, 8);
    cast_transpose<<<dim3(3 * D_ / 32, D_ / 32), tb, 0, stream>>>(w_qkv, wqkvt, D_, 3 * D_);

    // GEMM1: 4096 x 3072 x 1024, block 128x128 -> grid 768 = 3 blocks/CU
    gemm_k<2, 2, 0><<<dim3((B_ * T_) / 128, (3 * D_) / 128), 256, 0, stream>>>(
        xb, wqkvt, B_ * T_, 3 * D_, D_, qbuf, kbuf, vbuf, nullptr, nullptr);

    transpose_v<<<dim3(T_ / 64, B_ * H_), 256, 0, stream>>>(vbuf, vtbuf);

    // attn: per bh 9 single-strips + 7*2 split segments = 23 blocks; x32 bh = 736
    attn_kernel<<<23 * 32, 256, 0, stream>>>(qbuf, kbuf, vtbuf, ob, oP, mlP);
    // merge: 32*7*128 rows / 256 = 112 blocks
    attn_merge<<<112, 256, 0, stream>>>(oP, mlP, ob);

    cast_transpose<<<dim3(D_ / 32, D_ / 32), tb, 0, stream>>>(w_proj, wprojt, D_, D_);

    // GEMM2: 4096 x 1024 x 1024, block 64x128 -> grid 512 = 2 blocks/CU
    gemm_k<1, 2, 1><<<dim3((B_ * T_) / 64, D_ / 128), 256, 0, stream>>>(
        ob, wprojt, B_ * T_, D_, D_, nullptr, nullptr, nullptr, b_proj, out);
}

// Round 10
// 123.834 us; speedup vs baseline: 2.6503x; 2.6503x over previous
//
#include <hip/hip_runtime.h>
#include <hip/hip_bf16.h>

// Fused causal MHA: qkv proj -> flash attention (kv-split) -> out proj, bf16 MFMA.
// B=2 T=2048 D=1024 H=16 hd=64; softmax in log2 domain (scale 0.125*log2e in Q).

typedef __bf16 bf16;
typedef float f32x4 __attribute__((ext_vector_type(4)));
typedef float f32x16 __attribute__((ext_vector_type(16)));
typedef bf16 bf16x4 __attribute__((ext_vector_type(4)));
typedef bf16 bf16x8 __attribute__((ext_vector_type(8)));

#define B_ 2
#define T_ 2048
#define D_ 1024
#define H_ 16
#define HD_ 64
#define QSPLIT 9  // qt >= QSPLIT gets 2 kv-segments

__device__ __forceinline__ f32x16 mfma32(bf16x8 a, bf16x8 b, f32x16 c) {
    return __builtin_amdgcn_mfma_f32_32x32x16_bf16(a, b, c, 0, 0, 0);
}

// async global->LDS, 16B per lane (wave-uniform LDS base + lane*16)
__device__ __forceinline__ void gload16(void* l, const void* g) {
    __builtin_amdgcn_global_load_lds(
        (const __attribute__((address_space(1))) unsigned int*)g,
        (__attribute__((address_space(3))) unsigned int*)l, 16, 0, 0);
}

__device__ __forceinline__ f32x16 z16() {
    f32x16 v;
#pragma unroll
    for (int i = 0; i < 16; ++i) v[i] = 0.f;
    return v;
}

// ---------------- cast kernels ----------------
__global__ __launch_bounds__(256) void cast_f32_bf16(const float* __restrict__ in,
                                                     bf16* __restrict__ out, int n4) {
    int i = blockIdx.x * 256 + threadIdx.x;
    if (i < n4) {
        float4 v = ((const float4*)in)[i];
        bf16x4 o = { (bf16)v.x, (bf16)v.y, (bf16)v.z, (bf16)v.w };
        ((bf16x4*)out)[i] = o;
    }
}

// in [R][C] f32 -> out [C][R] bf16
__global__ __launch_bounds__(256) void cast_transpose(const float* __restrict__ in,
                                                      bf16* __restrict__ out, int R, int C) {
    __shared__ float tile[32][33];
    int cx = blockIdx.x * 32 + threadIdx.x;
    int r0 = blockIdx.y * 32;
#pragma unroll
    for (int j = 0; j < 32; j += 8)
        tile[threadIdx.y + j][threadIdx.x] = in[(size_t)(r0 + threadIdx.y + j) * C + cx];
    __syncthreads();
    int rx = r0 + threadIdx.x;
    int c0 = blockIdx.x * 32;
#pragma unroll
    for (int j = 0; j < 32; j += 8)
        out[(size_t)(c0 + threadIdx.y + j) * R + rx] = (bf16)tile[threadIdx.x][threadIdx.y + j];
}

// V [bh][T][64] bf16 -> Vt [bh][64][T] bf16 (64x64 tiles, conflict-free LDS)
__global__ __launch_bounds__(256) void transpose_v(const bf16* __restrict__ vb,
                                                   bf16* __restrict__ vt) {
    __shared__ bf16 st[64 * 65];
    const int bh = blockIdx.y;
    const int t0 = blockIdx.x * 64;
    const int tid = threadIdx.x;
#pragma unroll
    for (int c = 0; c < 2; ++c) {
        int cid = tid + c * 256;
        int r = cid >> 3, col = (cid & 7) * 8;
        bf16x8 v = *(const bf16x8*)&vb[((size_t)bh * T_ + t0 + r) * HD_ + col];
#pragma unroll
        for (int j = 0; j < 8; ++j) st[r * 65 + col + j] = v[j];
    }
    __syncthreads();
#pragma unroll
    for (int c = 0; c < 2; ++c) {
        int cid = tid + c * 256;
        int tg = cid & 7, d = cid >> 3;
        bf16x8 o;
#pragma unroll
        for (int j = 0; j < 8; ++j) o[j] = st[(tg * 8 + j) * 65 + d];
        *(bf16x8*)&vt[((size_t)bh * HD_ + d) * T_ + t0 + tg * 8] = o;
    }
}

// ---------------- GEMM: C[M,N] = A[M,K] * Bt[N,K]^T, 32x32x16 MFMA ----------------
template <int MW, int NWN, int EPI>
__global__ __launch_bounds__(256) void gemm_k(
    const bf16* __restrict__ A, const bf16* __restrict__ Bt,
    int M, int N, int K,
    bf16* __restrict__ qb, bf16* __restrict__ kb, bf16* __restrict__ vb,
    const float* __restrict__ bias, float* __restrict__ outf) {
    constexpr int BM = 64 * MW;
    constexpr int BN = 64 * NWN;
    __shared__ bf16 sA[BM * 64];
    __shared__ bf16 sB[BN * 64];
    const int tid = threadIdx.x;
    const int wave = tid >> 6, lane = tid & 63;
    const int ln = lane & 31, hi = lane >> 5;
    const int wr = (wave >> 1) * (32 * MW);
    const int wc = (wave & 1) * (32 * NWN);
    const int m0 = blockIdx.x * BM, n0 = blockIdx.y * BN;

    f32x16 acc[MW][NWN];
#pragma unroll
    for (int mi = 0; mi < MW; ++mi)
#pragma unroll
        for (int ni = 0; ni < NWN; ++ni) acc[mi][ni] = z16();

    for (int k0 = 0; k0 < K; k0 += 64) {
        __syncthreads();
#pragma unroll
        for (int j = 0; j < 2 * MW; ++j) {
            int c = tid + 256 * j;
            int r = c >> 3, g = (c & 7) ^ (r & 7);
            gload16(&sA[c * 8], A + (size_t)(m0 + r) * K + k0 + 8 * g);
        }
#pragma unroll
        for (int j = 0; j < 2 * NWN; ++j) {
            int c = tid + 256 * j;
            int r = c >> 3, g = (c & 7) ^ (r & 7);
            gload16(&sB[c * 8], Bt + (size_t)(n0 + r) * K + k0 + 8 * g);
        }
        __syncthreads();
#pragma unroll
        for (int s = 0; s < 4; ++s) {
            bf16x8 av[MW], bv[NWN];
#pragma unroll
            for (int mi = 0; mi < MW; ++mi) {
                int r = wr + mi * 32 + ln;
                av[mi] = *(const bf16x8*)((const char*)sA + r * 128 +
                                          ((((s << 1) | hi) ^ (r & 7)) << 4));
            }
#pragma unroll
            for (int ni = 0; ni < NWN; ++ni) {
                int r = wc + ni * 32 + ln;
                bv[ni] = *(const bf16x8*)((const char*)sB + r * 128 +
                                          ((((s << 1) | hi) ^ (r & 7)) << 4));
            }
#pragma unroll
            for (int mi = 0; mi < MW; ++mi)
#pragma unroll
                for (int ni = 0; ni < NWN; ++ni)
                    acc[mi][ni] = mfma32(av[mi], bv[ni], acc[mi][ni]);
        }
    }

    // epilogue: C/D layout col=lane&31, row=(r&3)+8*(r>>2)+4*hi
#pragma unroll
    for (int mi = 0; mi < MW; ++mi)
#pragma unroll
        for (int ni = 0; ni < NWN; ++ni)
#pragma unroll
            for (int r = 0; r < 16; ++r) {
                int row = m0 + wr + mi * 32 + (r & 3) + 8 * (r >> 2) + 4 * hi;
                int col = n0 + wc + ni * 32 + ln;
                float v = acc[mi][ni][r];
                if (EPI == 0) {
                    int part = col >> 10, h = (col >> 6) & 15, d = col & 63;
                    int b = row >> 11, t = row & (T_ - 1);
                    size_t idx = ((size_t)(b * H_ + h) * T_ + t) * HD_ + d;
                    bf16* dst = (part == 0) ? qb : (part == 1) ? kb : vb;
                    dst[idx] = (bf16)v;
                } else {
                    outf[(size_t)row * N + col] = v + bias[col];
                }
            }
}

// ---------------- flash attention: swapped-operand 32x32 MFMA + kv-split ------
// r7 structure (best measured) + r8's VALU cuts (ones-MFMA row-sum, max3 reduce).
// Straight-line loop, no lambdas holding vector refs (rule #20 / r9 lesson).
__device__ __forceinline__ bf16x8 kread(const char* base, int row, int s, int hi) {
    int b = (row * 128 + s * 32 + hi * 16) ^ ((row & 7) << 4);
    return *(const bf16x8*)(base + b);
}
__device__ __forceinline__ bf16x8 vread(const char* base, int row, int s, int hi) {
    int sw = (row & 7) << 4;
    int b0 = (row * 128 + s * 32 + hi * 8) ^ sw;
    int b1 = (row * 128 + s * 32 + hi * 8 + 16) ^ sw;
    bf16x4 lo = *(const bf16x4*)(base + b0);
    bf16x4 hi4 = *(const bf16x4*)(base + b1);
    return __builtin_shufflevector(lo, hi4, 0, 1, 2, 3, 4, 5, 6, 7);
}

__global__ __launch_bounds__(256, 3) void attn_kernel(
    const bf16* __restrict__ qb, const bf16* __restrict__ kb,
    const bf16* __restrict__ vtb, bf16* __restrict__ ob,
    bf16* __restrict__ oP, float2* __restrict__ mlP) {
    __shared__ bf16 sK2[2][4096];  // [64 kv][64 hd], 128B rows, chunk-swizzled
    __shared__ bf16 sV2[2][4096];  // [64 d][64 kv], 128B rows, chunk-swizzled

    const int bid = blockIdx.x;
    const int bh = bid & 31;
    const int sid = bid >> 5;  // 0..22
    int qt, seg, t0, t1;
    if (sid < QSPLIT) {
        qt = sid; seg = -1; t0 = 0; t1 = 2 * qt + 2;
    } else {
        int idx = sid - QSPLIT;
        qt = QSPLIT + (idx >> 1);
        seg = idx & 1;
        if (seg == 0) { t0 = 0; t1 = qt + 1; }
        else          { t0 = qt + 1; t1 = 2 * qt + 2; }
    }
    const int b = bh >> 4, h = bh & 15;
    const int tid = threadIdx.x, wave = tid >> 6, lane = tid & 63;
    const int ln = lane & 31, hi = lane >> 5;
    const int qs = qt * 128 + wave * 32;
    const int qrow = qs + ln;

    const bf16* Qg = qb + (size_t)bh * (T_ * HD_);
    const bf16* Kg = kb + (size_t)bh * (T_ * HD_);
    const bf16* Vtg = vtb + (size_t)bh * (HD_ * T_);

    // Q fragments, scale 0.125*log2(e) folded in (softmax in log2 domain)
    bf16x8 qf[4];
#pragma unroll
    for (int s = 0; s < 4; ++s) {
        bf16x8 v = *(const bf16x8*)&Qg[(size_t)qrow * HD_ + s * 16 + hi * 8];
#pragma unroll
        for (int e = 0; e < 8; ++e) v[e] = (bf16)((float)v[e] * 0.1803368801f);
        qf[s] = v;
    }
    bf16x8 ones;
#pragma unroll
    for (int e = 0; e < 8; ++e) ones[e] = (bf16)1.0f;

    // staging geometry: linear chunk c -> row r=c>>3, source chunk g=(c&7)^(r&7)
    const int rr0 = tid >> 3;
    const int gg = ((tid & 7) ^ (rr0 & 7)) * 8;

    // prologue: stage tile t0 into buffer 0 via async DMA
    {
        int kv0 = t0 * 64;
        gload16(&sK2[0][tid * 8], Kg + (size_t)(kv0 + rr0) * HD_ + gg);
        gload16(&sK2[0][(tid + 256) * 8], Kg + (size_t)(kv0 + rr0 + 32) * HD_ + gg);
        gload16(&sV2[0][tid * 8], Vtg + (size_t)rr0 * T_ + kv0 + gg);
        gload16(&sV2[0][(tid + 256) * 8], Vtg + (size_t)(rr0 + 32) * T_ + kv0 + gg);
    }
    __syncthreads();

    const float NINF = -__builtin_inff();
    f32x16 oA = z16(), oB = z16();
    float mR = NINF, lR = 0.f;
    int cur = 0;

    for (int t = t0; t < t1; ++t) {
        if ((t + 1) < t1) {  // async prefetch of next tile
            int kv0 = (t + 1) * 64;
            bf16* kd = sK2[cur ^ 1];
            bf16* vd = sV2[cur ^ 1];
            gload16(&kd[tid * 8], Kg + (size_t)(kv0 + rr0) * HD_ + gg);
            gload16(&kd[(tid + 256) * 8], Kg + (size_t)(kv0 + rr0 + 32) * HD_ + gg);
            gload16(&vd[tid * 8], Vtg + (size_t)rr0 * T_ + kv0 + gg);
            gload16(&vd[(tid + 256) * 8], Vtg + (size_t)(rr0 + 32) * T_ + kv0 + gg);
        }

        if (64 * t <= qs + 31) {  // wave not fully masked for this tile
            const char* kbase = (const char*)sK2[cur];
            const char* vbase = (const char*)sV2[cur];

            f32x16 p0 = z16(), p1 = z16();
            __builtin_amdgcn_s_setprio(1);
#pragma unroll
            for (int s = 0; s < 4; ++s) {
                bf16x8 a0 = kread(kbase, ln, s, hi);
                bf16x8 a1 = kread(kbase, ln + 32, s, hi);
                p0 = mfma32(a0, qf[s], p0);
                p1 = mfma32(a1, qf[s], p1);
            }
            __builtin_amdgcn_s_setprio(0);

            if (64 * t + 63 > qs) {  // diagonal tile: causal mask
                int kvb = 64 * t + 4 * hi;
#pragma unroll
                for (int r = 0; r < 16; ++r) {
                    int kvr = kvb + (r & 3) + 8 * (r >> 2);
                    if (kvr > qrow) p0[r] = NINF;
                    if (kvr + 32 > qrow) p1[r] = NINF;
                }
            }

            // max reduce: max3-shaped (16 fused ops)
            float mx0 = NINF, mx1 = NINF, mx2 = NINF, mx3 = NINF;
#pragma unroll
            for (int r = 0; r < 16; r += 4) {
                mx0 = fmaxf(fmaxf(p0[r], p1[r]), mx0);
                mx1 = fmaxf(fmaxf(p0[r + 1], p1[r + 1]), mx1);
                mx2 = fmaxf(fmaxf(p0[r + 2], p1[r + 2]), mx2);
                mx3 = fmaxf(fmaxf(p0[r + 3], p1[r + 3]), mx3);
            }
            float pm = fmaxf(fmaxf(mx0, mx1), fmaxf(mx2, mx3));
            pm = fmaxf(pm, __shfl_xor(pm, 32));

            // T13 defer-max: rescale only when the running max grows materially
            if (__any(pm > mR + 8.f)) {
                float mnew = fmaxf(mR, pm);
                float fac = exp2f(mR - mnew);
                lR *= fac;
#pragma unroll
                for (int r = 0; r < 16; ++r) { oA[r] *= fac; oB[r] *= fac; }
                mR = mnew;
            }

            // exp2 -> bf16 pack (row-sum via ones-MFMA below)
            bf16x8 pa0, pa1, pa2, pa3;
#pragma unroll
            for (int e = 0; e < 8; ++e) {
                pa0[e] = (bf16)exp2f(p0[e] - mR);
                pa1[e] = (bf16)exp2f(p0[8 + e] - mR);
                pa2[e] = (bf16)exp2f(p1[e] - mR);
                pa3[e] = (bf16)exp2f(p1[8 + e] - mR);
            }

            __builtin_amdgcn_s_setprio(1);
            // row-sum: D = ones * P^T -> every D row = column sums of P
            f32x16 sacc = mfma32(ones, pa0, z16());
            sacc = mfma32(ones, pa1, sacc);
            sacc = mfma32(ones, pa2, sacc);
            sacc = mfma32(ones, pa3, sacc);
#pragma unroll
            for (int s = 0; s < 4; ++s) {
                bf16x8 pas = (s == 0) ? pa0 : (s == 1) ? pa1 : (s == 2) ? pa2 : pa3;
                oA = mfma32(vread(vbase, ln, s, hi), pas, oA);
                oB = mfma32(vread(vbase, ln + 32, s, hi), pas, oB);
            }
            __builtin_amdgcn_s_setprio(0);
            lR += sacc[0];  // full 64-kv row sum (MFMA reduced across wave)
        }

        __syncthreads();  // drains prefetch DMA + LDS reads; flip buffers
        cur ^= 1;
    }

    if (seg < 0) {
        // final: normalized write to ob [B][T][H*64]
        float inv = 1.f / lR;
        bf16* orow = ob + ((size_t)(b * T_ + qrow)) * D_ + h * HD_;
#pragma unroll
        for (int g = 0; g < 4; ++g) {
            bf16x4 w, w2;
#pragma unroll
            for (int j = 0; j < 4; ++j) {
                w[j] = (bf16)(oA[4 * g + j] * inv);
                w2[j] = (bf16)(oB[4 * g + j] * inv);
            }
            *(bf16x4*)&orow[4 * hi + 8 * g] = w;
            *(bf16x4*)&orow[32 + 4 * hi + 8 * g] = w2;
        }
    } else {
        // partial: unnormalized O + (m,l)
        int row = wave * 32 + ln;
        size_t sbase = (((size_t)bh * (16 - QSPLIT) + (qt - QSPLIT)) * 2 + seg);
        bf16* prow = oP + (sbase * 128 + row) * 64;
#pragma unroll
        for (int g = 0; g < 4; ++g) {
            bf16x4 w, w2;
#pragma unroll
            for (int j = 0; j < 4; ++j) {
                w[j] = (bf16)oA[4 * g + j];
                w2[j] = (bf16)oB[4 * g + j];
            }
            *(bf16x4*)&prow[4 * hi + 8 * g] = w;
            *(bf16x4*)&prow[32 + 4 * hi + 8 * g] = w2;
        }
        if (hi == 0) mlP[sbase * 128 + row] = make_float2(mR, lR);
    }
}

// merge 2 kv-segments per split q-strip: one thread per q-row
__global__ __launch_bounds__(256) void attn_merge(
    const bf16* __restrict__ oP, const float2* __restrict__ mlP,
    bf16* __restrict__ ob) {
    constexpr int NQS = 16 - QSPLIT;  // 7
    int gid = blockIdx.x * 256 + threadIdx.x;  // 32*NQS*128 total
    int bh = gid / (NQS * 128);
    int rem = gid - bh * (NQS * 128);
    int qi = rem >> 7, row = rem & 127;
    int b = bh >> 4, h = bh & 15;
    int t = (QSPLIT + qi) * 128 + row;
    size_t sbase = ((size_t)bh * NQS + qi) * 2;
    float2 ml0 = mlP[(sbase + 0) * 128 + row];
    float2 ml1 = mlP[(sbase + 1) * 128 + row];
    float ms = fmaxf(ml0.x, ml1.x);
    float w0 = exp2f(ml0.x - ms), w1 = exp2f(ml1.x - ms);
    float inv = 1.f / (ml0.y * w0 + ml1.y * w1);
    w0 *= inv; w1 *= inv;
    const bf16* r0 = oP + ((sbase + 0) * 128 + row) * 64;
    const bf16* r1 = oP + ((sbase + 1) * 128 + row) * 64;
    bf16* dst = ob + ((size_t)(b * T_ + t)) * D_ + h * HD_;
#pragma unroll
    for (int g = 0; g < 8; ++g) {
        bf16x8 a = *(const bf16x8*)&r0[g * 8];
        bf16x8 c = *(const bf16x8*)&r1[g * 8];
        bf16x8 o;
#pragma unroll
        for (int j = 0; j < 8; ++j)
            o[j] = (bf16)((float)a[j] * w0 + (float)c[j] * w1);
        *(bf16x8*)&dst[g * 8] = o;
    }
}

// ---------------- launch ----------------
extern "C" void kernel_launch(void* const* d_in, const int* in_sizes, int n_in,
                              void* d_out, int out_size, void* d_ws, size_t ws_size,
                              hipStream_t stream) {
    const float* x = (const float*)d_in[0];
    const float* w_qkv = (const float*)d_in[1];
    const float* w_proj = (const float*)d_in[2];
    const float* b_proj = (const float*)d_in[3];
    float* out = (float*)d_out;
    char* ws = (char*)d_ws;

    // ws layout (40 MB total, aliased by liveness):
    bf16* xb = (bf16*)(ws);                 // [4096][1024]  8MB ; dead after GEMM1
    bf16* ob = (bf16*)(ws);                 // alias: attn out (written after xb dead)
    bf16* wqkvt = (bf16*)(ws + 8388608);    // [3072][1024]  6MB ; dead after GEMM1
    bf16* vtbuf = (bf16*)(ws + 8388608);    // alias: [bh][64][T] 8MB
    bf16* qbuf = (bf16*)(ws + 16777216);    // [bh][T][64]   8MB
    bf16* wprojt = (bf16*)(ws + 16777216);  // alias: [1024][1024] 2MB (after attn)
    bf16* kbuf = (bf16*)(ws + 25165824);    // [bh][T][64]   8MB
    bf16* vbuf = (bf16*)(ws + 33554432);    // [bh][T][64]   8MB ; dead after transpose_v
    bf16* oP = (bf16*)(ws + 33554432);      // alias: partial O [32][7][2][128][64] 7.34MB
    float2* mlP = (float2*)(ws + 33554432 + 7340032);  // [32][7][2][128] 448KB

    cast_f32_bf16<<<4096, 256, 0, stream>>>(x, xb, (B_ * T_ * D_) / 4);
    dim3 tb(32, 8);
    cast_transpose<<<dim3(3 * D_ / 32, D_ / 32), tb, 0, stream>>>(w_qkv, wqkvt, D_, 3 * D_);

    // GEMM1: 4096 x 3072 x 1024, block 128x128 -> grid 768 = 3 blocks/CU
    gemm_k<2, 2, 0><<<dim3((B_ * T_) / 128, (3 * D_) / 128), 256, 0, stream>>>(
        xb, wqkvt, B_ * T_, 3 * D_, D_, qbuf, kbuf, vbuf, nullptr, nullptr);

    transpose_v<<<dim3(T_ / 64, B_ * H_), 256, 0, stream>>>(vbuf, vtbuf);

    // attn: per bh 9 single-strips + 7*2 split segments = 23 blocks; x32 bh = 736
    attn_kernel<<<23 * 32, 256, 0, stream>>>(qbuf, kbuf, vtbuf, ob, oP, mlP);
    // merge: 32*7*128 rows / 256 = 112 blocks
    attn_merge<<<112, 256, 0, stream>>>(oP, mlP, ob);

    cast_transpose<<<dim3(D_ / 32, D_ / 32), tb, 0, stream>>>(w_proj, wprojt, D_, D_);

    // GEMM2: 4096 x 1024 x 1024, block 64x128 -> grid 512 = 2 blocks/CU
    gemm_k<1, 2, 1><<<dim3((B_ * T_) / 64, D_ / 128), 256, 0, stream>>>(
        ob, wprojt, B_ * T_, D_, D_, nullptr, nullptr, nullptr, b_proj, out);
}